// Round 3
// baseline (587.093 us; speedup 1.0000x reference)
//
#include <hip/hip_runtime.h>
#include <stdint.h>

#define Sq   2176
#define Dm   3072
#define NDm  9216
#define NH   24
#define HDm  128
#define BLKR 1152   // S - COND
#define KVSPLIT 4
#define KVCHUNK (Sq / KVSPLIT)   // 544 = 17*32

typedef __attribute__((ext_vector_type(8))) __bf16 bf16x8;
typedef __attribute__((ext_vector_type(4))) float f32x4;
typedef __attribute__((ext_vector_type(8))) unsigned short ushort8;

__device__ __forceinline__ unsigned short f2bf(float x) {
  unsigned u = __builtin_bit_cast(unsigned, x);
  u += 0x7FFFu + ((u >> 16) & 1u);   // RNE; inputs are finite randoms
  return (unsigned short)(u >> 16);
}

// ---------------- f32 -> bf16 conversion, 8 elems/thread ----------------
__global__ void cvt_kernel(const float* __restrict__ src,
                           unsigned short* __restrict__ dst, int n8) {
  int i = blockIdx.x * blockDim.x + threadIdx.x;
  if (i >= n8) return;
  const float4* s4 = (const float4*)src + (size_t)i * 2;
  float4 a = s4[0], b = s4[1];
  ushort8 o;
  o[0]=f2bf(a.x); o[1]=f2bf(a.y); o[2]=f2bf(a.z); o[3]=f2bf(a.w);
  o[4]=f2bf(b.x); o[5]=f2bf(b.y); o[6]=f2bf(b.z); o[7]=f2bf(b.w);
  *((ushort8*)dst + i) = o;
}

// ---------------- fused QKV GEMM: C[s][n] = sum_e hs[s][e]*W[n][e] + bias ---
__global__ __launch_bounds__(256) void gemm_kernel(
    const unsigned short* __restrict__ A,
    const unsigned short* __restrict__ B,
    const float* __restrict__ bq, const float* __restrict__ bk,
    const float* __restrict__ bv, float* __restrict__ C) {
  __shared__ __attribute__((aligned(16))) unsigned short aLds[128 * 32];
  __shared__ __attribute__((aligned(16))) unsigned short bLds[128 * 32];
  int t = threadIdx.x;
  int wid = t >> 6, lane = t & 63;
  int lr = lane & 15, lg = lane >> 4;
  int m0 = blockIdx.y * 128, n0 = blockIdx.x * 128;
  int wr = wid >> 1, wc = wid & 1;

  f32x4 acc[4][4];
#pragma unroll
  for (int m = 0; m < 4; m++)
#pragma unroll
    for (int n = 0; n < 4; n++) acc[m][n] = (f32x4){0.f, 0.f, 0.f, 0.f};

  int row = t >> 2, colk = (t & 3) * 8;
  const unsigned short* ga0 = A + (size_t)(m0 + row) * Dm + colk;
  const unsigned short* ga1 = A + (size_t)(m0 + 64 + row) * Dm + colk;
  const unsigned short* gb0 = B + (size_t)(n0 + row) * Dm + colk;
  const unsigned short* gb1 = B + (size_t)(n0 + 64 + row) * Dm + colk;

  for (int kt = 0; kt < Dm / 32; kt++) {
    __builtin_amdgcn_global_load_lds(
        (const __attribute__((address_space(1))) void*)ga0,
        (__attribute__((address_space(3))) void*)(aLds + wid * 512), 16, 0, 0);
    __builtin_amdgcn_global_load_lds(
        (const __attribute__((address_space(1))) void*)ga1,
        (__attribute__((address_space(3))) void*)(aLds + 2048 + wid * 512), 16, 0, 0);
    __builtin_amdgcn_global_load_lds(
        (const __attribute__((address_space(1))) void*)gb0,
        (__attribute__((address_space(3))) void*)(bLds + wid * 512), 16, 0, 0);
    __builtin_amdgcn_global_load_lds(
        (const __attribute__((address_space(1))) void*)gb1,
        (__attribute__((address_space(3))) void*)(bLds + 2048 + wid * 512), 16, 0, 0);
    ga0 += 32; ga1 += 32; gb0 += 32; gb1 += 32;
    __syncthreads();

    bf16x8 af[4], bf[4];
#pragma unroll
    for (int m = 0; m < 4; m++)
      af[m] = *(const bf16x8*)&aLds[(wr * 64 + m * 16 + lr) * 32 + lg * 8];
#pragma unroll
    for (int n = 0; n < 4; n++)
      bf[n] = *(const bf16x8*)&bLds[(wc * 64 + n * 16 + lr) * 32 + lg * 8];
#pragma unroll
    for (int m = 0; m < 4; m++)
#pragma unroll
      for (int n = 0; n < 4; n++)
        acc[m][n] = __builtin_amdgcn_mfma_f32_16x16x32_bf16(af[m], bf[n], acc[m][n], 0, 0, 0);
    __syncthreads();
  }

#pragma unroll
  for (int m = 0; m < 4; m++)
#pragma unroll
    for (int n = 0; n < 4; n++) {
      int col = n0 + wc * 64 + n * 16 + lr;
      float bias = col < 3072 ? bq[col] : (col < 6144 ? bk[col - 3072] : bv[col - 6144]);
#pragma unroll
      for (int i = 0; i < 4; i++) {
        int r = m0 + wr * 64 + m * 16 + lg * 4 + i;
        C[(size_t)r * NDm + col] = acc[m][n][i] + bias;
      }
    }
}

// ---------------- LoRA for k,v only (q LoRA only touches discarded rows) ---
__global__ __launch_bounds__(256) void lora_kernel(
    const float* __restrict__ hs,
    const float* __restrict__ k_down, const float* __restrict__ k_up,
    const float* __restrict__ v_down, const float* __restrict__ v_up,
    float* __restrict__ qkv) {
  int srow = BLKR + blockIdx.x;
  int t = threadIdx.x;
  __shared__ float hsl[Dm];
  __shared__ float tl[32];
  for (int e = t; e < Dm; e += 256) hsl[e] = hs[(size_t)srow * Dm + e];
  __syncthreads();
  int dot = t >> 3, part = t & 7;
  int mat = dot >> 4, j = dot & 15;
  const float* down = mat ? v_down : k_down;
  float p = 0.f;
  for (int e = part; e < Dm; e += 8) p += hsl[e] * down[j * Dm + e];
  p += __shfl_xor(p, 1, 64);
  p += __shfl_xor(p, 2, 64);
  p += __shfl_xor(p, 4, 64);
  if (part == 0) tl[dot] = p;
  __syncthreads();
  float tk[16], tv[16];
#pragma unroll
  for (int jj = 0; jj < 16; jj++) { tk[jj] = tl[jj]; tv[jj] = tl[16 + jj]; }
  for (int n = t; n < Dm; n += 256) {
    float ak = 0.f, av = 0.f;
#pragma unroll
    for (int jj = 0; jj < 16; jj++) {
      ak += tk[jj] * k_up[n * 16 + jj];
      av += tv[jj] * v_up[n * 16 + jj];
    }
    qkv[(size_t)srow * NDm + 3072 + n] += ak;
    qkv[(size_t)srow * NDm + 6144 + n] += av;
  }
}

// ---------------- RMSNorm + RoPE -> bf16 head-major q,k ----------------
__global__ __launch_bounds__(64) void prep_kernel(
    const float* __restrict__ qkv,
    const float* __restrict__ nqw, const float* __restrict__ nkw,
    const float* __restrict__ rc, const float* __restrict__ rs,
    unsigned short* __restrict__ qh, unsigned short* __restrict__ kh) {
  int s = blockIdx.x, h = blockIdx.y;
  int l = threadIdx.x;
  int d0 = l * 2;
  float c0 = rc[s * 128 + d0], c1 = rc[s * 128 + d0 + 1];
  float s0 = rs[s * 128 + d0], s1 = rs[s * 128 + d0 + 1];

  { // k: all rows
    const float* kp = qkv + (size_t)s * NDm + 3072 + h * 128;
    float2 x = *(const float2*)(kp + d0);
    float ss = x.x * x.x + x.y * x.y;
#pragma unroll
    for (int m = 1; m < 64; m <<= 1) ss += __shfl_xor(ss, m, 64);
    float r = rsqrtf(ss * (1.f / 128.f) + 1e-6f);
    float xn0 = x.x * r * nkw[d0], xn1 = x.y * r * nkw[d0 + 1];
    ushort2 o = make_ushort2(f2bf(xn0 * c0 - xn1 * s0), f2bf(xn1 * c1 + xn0 * s1));
    *(ushort2*)&kh[((size_t)h * Sq + s) * 128 + d0] = o;
  }
  if (s < BLKR) { // q: only output rows
    const float* qp = qkv + (size_t)s * NDm + h * 128;
    float2 x = *(const float2*)(qp + d0);
    float ss = x.x * x.x + x.y * x.y;
#pragma unroll
    for (int m = 1; m < 64; m <<= 1) ss += __shfl_xor(ss, m, 64);
    float r = rsqrtf(ss * (1.f / 128.f) + 1e-6f);
    float xn0 = x.x * r * nqw[d0], xn1 = x.y * r * nqw[d0 + 1];
    ushort2 o = make_ushort2(f2bf(xn0 * c0 - xn1 * s0), f2bf(xn1 * c1 + xn0 * s1));
    *(ushort2*)&qh[((size_t)h * BLKR + s) * 128 + d0] = o;
  }
}

// ---------------- v transpose to V^T per head (bf16) ----------------
__global__ __launch_bounds__(256) void vt_kernel(const float* __restrict__ qkv,
                                                 unsigned short* __restrict__ vt) {
  int st = blockIdx.x, dt = blockIdx.y, h = blockIdx.z;
  int tx = threadIdx.x & 31, ty = threadIdx.x >> 5;
  __shared__ float ld[32][33];
  int s0 = st * 32, d0 = dt * 32;
#pragma unroll
  for (int p = 0; p < 4; p++) {
    int ss = ty + p * 8;
    ld[ss][tx] = qkv[(size_t)(s0 + ss) * NDm + 6144 + h * 128 + d0 + tx];
  }
  __syncthreads();
#pragma unroll
  for (int p = 0; p < 4; p++) {
    int dd = ty + p * 8;
    vt[((size_t)h * 128 + d0 + dd) * Sq + s0 + tx] = f2bf(ld[tx][dd]);
  }
}

// ---------------- flash attention, split-KV in block ----------------
// 4 waves/block: same 16 q rows, each wave a 544-key chunk; in-LDS combine.
// Wave-uniform running max M (cancels in acc/l), deferred rescale (THR=8).
__global__ __launch_bounds__(256, 6) void attn_kernel(
    const unsigned short* __restrict__ qh,  // [NH][1152][128]
    const unsigned short* __restrict__ kh,  // [NH][2176][128]
    const unsigned short* __restrict__ vt,  // [NH][128][2176]
    float* __restrict__ out) {              // [1152][3072] f32
  int h = blockIdx.y;
  int t = threadIdx.x;
  int w = t >> 6, lane = t & 63;
  int lr = lane & 15, lg = lane >> 4;
  int q0 = blockIdx.x * 16;

  __shared__ __attribute__((aligned(16))) unsigned short pl[4][16][40]; // padded stride
  __shared__ float accs[4][16][68];
  __shared__ float lsh[4][16];
  __shared__ float msh[4];

  const unsigned short* qb = qh + ((size_t)h * BLKR + q0) * 128;
  bf16x8 aq[4];
#pragma unroll
  for (int m = 0; m < 4; m++)
    aq[m] = *(const bf16x8*)(qb + (size_t)lr * 128 + m * 32 + lg * 8);

  f32x4 acc[8];
#pragma unroll
  for (int o = 0; o < 8; o++) acc[o] = (f32x4){0.f, 0.f, 0.f, 0.f};
  float lsum[4] = {0.f, 0.f, 0.f, 0.f};
  float M = -3.0e38f;

  const unsigned short* kb = kh + ((size_t)h * Sq + w * KVCHUNK) * 128;
  const unsigned short* vb = vt + (size_t)h * 128 * Sq + w * KVCHUNK;
  const float sc = 0.08838834764831845f;   // 1/sqrt(128)
  const float L2E = 1.4426950408889634f;

  for (int kt = 0; kt < KVCHUNK / 32; kt++) {
    int kbase = kt * 32;
    f32x4 s2[2];
    s2[0] = (f32x4){0.f, 0.f, 0.f, 0.f};
    s2[1] = (f32x4){0.f, 0.f, 0.f, 0.f};
#pragma unroll
    for (int tt = 0; tt < 2; tt++) {
      const unsigned short* kr = kb + (size_t)(kbase + tt * 16 + lr) * 128 + lg * 8;
#pragma unroll
      for (int m = 0; m < 4; m++) {
        bf16x8 bk8 = *(const bf16x8*)(kr + m * 32);
        s2[tt] = __builtin_amdgcn_mfma_f32_16x16x32_bf16(aq[m], bk8, s2[tt], 0, 0, 0);
      }
    }
    // wave-wide tile max (scaled)
    float tm = fmaxf(fmaxf(fmaxf(s2[0][0], s2[0][1]), fmaxf(s2[0][2], s2[0][3])),
                     fmaxf(fmaxf(s2[1][0], s2[1][1]), fmaxf(s2[1][2], s2[1][3])));
#pragma unroll
    for (int d = 1; d < 64; d <<= 1) tm = fmaxf(tm, __shfl_xor(tm, d, 64));
    tm *= sc;
    if (tm > M + 8.0f) {           // deferred rescale, wave-uniform branch
      float r = exp2f((M - tm) * L2E);
      M = tm;
#pragma unroll
      for (int o = 0; o < 8; o++)
#pragma unroll
        for (int i = 0; i < 4; i++) acc[o][i] *= r;
#pragma unroll
      for (int i = 0; i < 4; i++) lsum[i] *= r;
    }
    float ea = sc * L2E, eb = -M * L2E;
#pragma unroll
    for (int tt = 0; tt < 2; tt++)
#pragma unroll
      for (int i = 0; i < 4; i++) {
        float p = exp2f(fmaf(s2[tt][i], ea, eb));
        lsum[i] += p;
        pl[w][lg * 4 + i][tt * 16 + lr] = f2bf(p);
      }
    bf16x8 ap = *(const bf16x8*)&pl[w][lr][lg * 8];
#pragma unroll
    for (int o = 0; o < 8; o++) {
      bf16x8 bv8 = *(const bf16x8*)(vb + (size_t)(o * 16 + lr) * Sq + kbase + lg * 8);
      acc[o] = __builtin_amdgcn_mfma_f32_16x16x32_bf16(ap, bv8, acc[o], 0, 0, 0);
    }
  }

  // ---- in-block combine ----
#pragma unroll
  for (int i = 0; i < 4; i++) {
#pragma unroll
    for (int d = 1; d < 16; d <<= 1) lsum[i] += __shfl_xor(lsum[i], d, 64);
  }
  if (lr == 0) {
#pragma unroll
    for (int i = 0; i < 4; i++) lsh[w][lg * 4 + i] = lsum[i];
  }
  if (lane == 0) msh[w] = M;
  __syncthreads();
  float Mg = fmaxf(fmaxf(msh[0], msh[1]), fmaxf(msh[2], msh[3]));
  float wself = exp2f((msh[w] - Mg) * L2E);
  float wvec[4];
#pragma unroll
  for (int p = 0; p < 4; p++) wvec[p] = exp2f((msh[p] - Mg) * L2E);
#pragma unroll
  for (int o = 0; o < 8; o++)
#pragma unroll
    for (int i = 0; i < 4; i++) acc[o][i] *= wself;

  int col = t & 63;
#pragma unroll
  for (int half = 0; half < 2; half++) {
#pragma unroll
    for (int o = 0; o < 4; o++) {
      int oo = half * 4 + o;
#pragma unroll
      for (int i = 0; i < 4; i++)
        accs[w][lg * 4 + i][o * 16 + lr] = acc[oo][i];
    }
    __syncthreads();
#pragma unroll
    for (int rep = 0; rep < 4; rep++) {
      int row = rep * 4 + w;
      float s = accs[0][row][col] + accs[1][row][col] + accs[2][row][col] + accs[3][row][col];
      float Ls = wvec[0] * lsh[0][row] + wvec[1] * lsh[1][row] +
                 wvec[2] * lsh[2][row] + wvec[3] * lsh[3][row];
      out[(size_t)(q0 + row) * 3072 + h * 128 + half * 64 + col] = s / Ls;
    }
    __syncthreads();
  }
}

extern "C" void kernel_launch(void* const* d_in, const int* in_sizes, int n_in,
                              void* d_out, int out_size, void* d_ws, size_t ws_size,
                              hipStream_t stream) {
  const float* hs  = (const float*)d_in[0];
  const float* Wq  = (const float*)d_in[1];
  const float* bq  = (const float*)d_in[2];
  const float* Wk  = (const float*)d_in[3];
  const float* bk  = (const float*)d_in[4];
  const float* Wv  = (const float*)d_in[5];
  const float* bv  = (const float*)d_in[6];
  const float* k_down = (const float*)d_in[9];
  const float* k_up   = (const float*)d_in[10];
  const float* v_down = (const float*)d_in[11];
  const float* v_up   = (const float*)d_in[12];
  const float* nqw = (const float*)d_in[13];
  const float* nkw = (const float*)d_in[14];
  const float* rc  = (const float*)d_in[15];
  const float* rsn = (const float*)d_in[16];
  float* out = (float*)d_out;

  char* ws = (char*)d_ws;
  unsigned short* hsb = (unsigned short*)(ws + 0);          // 13,369,344 B
  unsigned short* wb  = (unsigned short*)(ws + 13369344);   // 56,623,104 B
  float*          qkv = (float*)(ws + 69992448);            // 80,216,064 B
  unsigned short* qh  = (unsigned short*)(ws + 150208512);  //  7,077,888 B
  unsigned short* kh  = (unsigned short*)(ws + 157286400);  // 13,369,344 B
  unsigned short* vtb = (unsigned short*)(ws + 170655744);  // 13,369,344 B

  const int n8_hs = Sq * Dm / 8;
  const int n8_w  = Dm * Dm / 8;
  cvt_kernel<<<dim3((n8_hs + 255) / 256), 256, 0, stream>>>(hs, hsb, n8_hs);
  cvt_kernel<<<dim3((n8_w + 255) / 256), 256, 0, stream>>>(Wq, wb, n8_w);
  cvt_kernel<<<dim3((n8_w + 255) / 256), 256, 0, stream>>>(Wk, wb + (size_t)Dm * Dm, n8_w);
  cvt_kernel<<<dim3((n8_w + 255) / 256), 256, 0, stream>>>(Wv, wb + (size_t)2 * Dm * Dm, n8_w);

  gemm_kernel<<<dim3(NDm / 128, Sq / 128), 256, 0, stream>>>(hsb, wb, bq, bk, bv, qkv);
  lora_kernel<<<dim3(Sq - BLKR), 256, 0, stream>>>(hs, k_down, k_up, v_down, v_up, qkv);
  prep_kernel<<<dim3(Sq, NH), 64, 0, stream>>>(qkv, nqw, nkw, rc, rsn, qh, kh);
  vt_kernel<<<dim3(Sq / 32, HDm / 32, NH), 256, 0, stream>>>(qkv, vtb);
  attn_kernel<<<dim3(BLKR / 16, NH), 256, 0, stream>>>(qh, kh, vtb, out);
}

// Round 4
// 392.998 us; speedup vs baseline: 1.4939x; 1.4939x over previous
//
#include <hip/hip_runtime.h>
#include <stdint.h>

#define Sq   2176
#define Dm   3072
#define NDm  9216
#define NH   24
#define HDm  128
#define BLKR 1152   // S - COND
#define NT   (Sq / 64)   // 34 KV tiles of 64

typedef __attribute__((ext_vector_type(8))) __bf16 bf16x8;
typedef __attribute__((ext_vector_type(4))) float f32x4;
typedef __attribute__((ext_vector_type(8))) unsigned short ushort8;

__device__ __forceinline__ unsigned short f2bf(float x) {
  unsigned u = __builtin_bit_cast(unsigned, x);
  u += 0x7FFFu + ((u >> 16) & 1u);   // RNE; inputs are finite randoms
  return (unsigned short)(u >> 16);
}

// ---------------- f32 -> bf16 conversion, 8 elems/thread ----------------
__global__ void cvt_kernel(const float* __restrict__ src,
                           unsigned short* __restrict__ dst, int n8) {
  int i = blockIdx.x * blockDim.x + threadIdx.x;
  if (i >= n8) return;
  const float4* s4 = (const float4*)src + (size_t)i * 2;
  float4 a = s4[0], b = s4[1];
  ushort8 o;
  o[0]=f2bf(a.x); o[1]=f2bf(a.y); o[2]=f2bf(a.z); o[3]=f2bf(a.w);
  o[4]=f2bf(b.x); o[5]=f2bf(b.y); o[6]=f2bf(b.z); o[7]=f2bf(b.w);
  *((ushort8*)dst + i) = o;
}

// ---------------- fused QKV GEMM: C[s][n] = sum_e hs[s][e]*W[n][e] + bias ---
__global__ __launch_bounds__(256) void gemm_kernel(
    const unsigned short* __restrict__ A,
    const unsigned short* __restrict__ B,
    const float* __restrict__ bq, const float* __restrict__ bk,
    const float* __restrict__ bv, float* __restrict__ C) {
  __shared__ __attribute__((aligned(16))) unsigned short aLds[128 * 32];
  __shared__ __attribute__((aligned(16))) unsigned short bLds[128 * 32];
  int t = threadIdx.x;
  int wid = t >> 6, lane = t & 63;
  int lr = lane & 15, lg = lane >> 4;
  int m0 = blockIdx.y * 128, n0 = blockIdx.x * 128;
  int wr = wid >> 1, wc = wid & 1;

  f32x4 acc[4][4];
#pragma unroll
  for (int m = 0; m < 4; m++)
#pragma unroll
    for (int n = 0; n < 4; n++) acc[m][n] = (f32x4){0.f, 0.f, 0.f, 0.f};

  int row = t >> 2, colk = (t & 3) * 8;
  const unsigned short* ga0 = A + (size_t)(m0 + row) * Dm + colk;
  const unsigned short* ga1 = A + (size_t)(m0 + 64 + row) * Dm + colk;
  const unsigned short* gb0 = B + (size_t)(n0 + row) * Dm + colk;
  const unsigned short* gb1 = B + (size_t)(n0 + 64 + row) * Dm + colk;

  for (int kt = 0; kt < Dm / 32; kt++) {
    __builtin_amdgcn_global_load_lds(
        (const __attribute__((address_space(1))) void*)ga0,
        (__attribute__((address_space(3))) void*)(aLds + wid * 512), 16, 0, 0);
    __builtin_amdgcn_global_load_lds(
        (const __attribute__((address_space(1))) void*)ga1,
        (__attribute__((address_space(3))) void*)(aLds + 2048 + wid * 512), 16, 0, 0);
    __builtin_amdgcn_global_load_lds(
        (const __attribute__((address_space(1))) void*)gb0,
        (__attribute__((address_space(3))) void*)(bLds + wid * 512), 16, 0, 0);
    __builtin_amdgcn_global_load_lds(
        (const __attribute__((address_space(1))) void*)gb1,
        (__attribute__((address_space(3))) void*)(bLds + 2048 + wid * 512), 16, 0, 0);
    ga0 += 32; ga1 += 32; gb0 += 32; gb1 += 32;
    __syncthreads();

    bf16x8 af[4], bf[4];
#pragma unroll
    for (int m = 0; m < 4; m++)
      af[m] = *(const bf16x8*)&aLds[(wr * 64 + m * 16 + lr) * 32 + lg * 8];
#pragma unroll
    for (int n = 0; n < 4; n++)
      bf[n] = *(const bf16x8*)&bLds[(wc * 64 + n * 16 + lr) * 32 + lg * 8];
#pragma unroll
    for (int m = 0; m < 4; m++)
#pragma unroll
      for (int n = 0; n < 4; n++)
        acc[m][n] = __builtin_amdgcn_mfma_f32_16x16x32_bf16(af[m], bf[n], acc[m][n], 0, 0, 0);
    __syncthreads();
  }

#pragma unroll
  for (int m = 0; m < 4; m++)
#pragma unroll
    for (int n = 0; n < 4; n++) {
      int col = n0 + wc * 64 + n * 16 + lr;
      float bias = col < 3072 ? bq[col] : (col < 6144 ? bk[col - 3072] : bv[col - 6144]);
#pragma unroll
      for (int i = 0; i < 4; i++) {
        int r = m0 + wr * 64 + m * 16 + lg * 4 + i;
        C[(size_t)r * NDm + col] = acc[m][n][i] + bias;
      }
    }
}

// ---------------- LoRA for k,v only (q LoRA only touches discarded rows) ---
__global__ __launch_bounds__(256) void lora_kernel(
    const float* __restrict__ hs,
    const float* __restrict__ k_down, const float* __restrict__ k_up,
    const float* __restrict__ v_down, const float* __restrict__ v_up,
    float* __restrict__ qkv) {
  int srow = BLKR + blockIdx.x;
  int t = threadIdx.x;
  __shared__ float hsl[Dm];
  __shared__ float tl[32];
  for (int e = t; e < Dm; e += 256) hsl[e] = hs[(size_t)srow * Dm + e];
  __syncthreads();
  int dot = t >> 3, part = t & 7;
  int mat = dot >> 4, j = dot & 15;
  const float* down = mat ? v_down : k_down;
  float p = 0.f;
  for (int e = part; e < Dm; e += 8) p += hsl[e] * down[j * Dm + e];
  p += __shfl_xor(p, 1, 64);
  p += __shfl_xor(p, 2, 64);
  p += __shfl_xor(p, 4, 64);
  if (part == 0) tl[dot] = p;
  __syncthreads();
  float tk[16], tv[16];
#pragma unroll
  for (int jj = 0; jj < 16; jj++) { tk[jj] = tl[jj]; tv[jj] = tl[16 + jj]; }
  for (int n = t; n < Dm; n += 256) {
    float ak = 0.f, av = 0.f;
#pragma unroll
    for (int jj = 0; jj < 16; jj++) {
      ak += tk[jj] * k_up[n * 16 + jj];
      av += tv[jj] * v_up[n * 16 + jj];
    }
    qkv[(size_t)srow * NDm + 3072 + n] += ak;
    qkv[(size_t)srow * NDm + 6144 + n] += av;
  }
}

// ---------------- RMSNorm + RoPE -> bf16 head-major q,k ----------------
__global__ __launch_bounds__(64) void prep_kernel(
    const float* __restrict__ qkv,
    const float* __restrict__ nqw, const float* __restrict__ nkw,
    const float* __restrict__ rc, const float* __restrict__ rs,
    unsigned short* __restrict__ qh, unsigned short* __restrict__ kh) {
  int s = blockIdx.x, h = blockIdx.y;
  int l = threadIdx.x;
  int d0 = l * 2;
  float c0 = rc[s * 128 + d0], c1 = rc[s * 128 + d0 + 1];
  float s0 = rs[s * 128 + d0], s1 = rs[s * 128 + d0 + 1];

  { // k: all rows
    const float* kp = qkv + (size_t)s * NDm + 3072 + h * 128;
    float2 x = *(const float2*)(kp + d0);
    float ss = x.x * x.x + x.y * x.y;
#pragma unroll
    for (int m = 1; m < 64; m <<= 1) ss += __shfl_xor(ss, m, 64);
    float r = rsqrtf(ss * (1.f / 128.f) + 1e-6f);
    float xn0 = x.x * r * nkw[d0], xn1 = x.y * r * nkw[d0 + 1];
    ushort2 o = make_ushort2(f2bf(xn0 * c0 - xn1 * s0), f2bf(xn1 * c1 + xn0 * s1));
    *(ushort2*)&kh[((size_t)h * Sq + s) * 128 + d0] = o;
  }
  if (s < BLKR) { // q: only output rows
    const float* qp = qkv + (size_t)s * NDm + h * 128;
    float2 x = *(const float2*)(qp + d0);
    float ss = x.x * x.x + x.y * x.y;
#pragma unroll
    for (int m = 1; m < 64; m <<= 1) ss += __shfl_xor(ss, m, 64);
    float r = rsqrtf(ss * (1.f / 128.f) + 1e-6f);
    float xn0 = x.x * r * nqw[d0], xn1 = x.y * r * nqw[d0 + 1];
    ushort2 o = make_ushort2(f2bf(xn0 * c0 - xn1 * s0), f2bf(xn1 * c1 + xn0 * s1));
    *(ushort2*)&qh[((size_t)h * BLKR + s) * 128 + d0] = o;
  }
}

// ---------------- v transpose to V^T per head (bf16) ----------------
__global__ __launch_bounds__(256) void vt_kernel(const float* __restrict__ qkv,
                                                 unsigned short* __restrict__ vt) {
  int st = blockIdx.x, dt = blockIdx.y, h = blockIdx.z;
  int tx = threadIdx.x & 31, ty = threadIdx.x >> 5;
  __shared__ float ld[32][33];
  int s0 = st * 32, d0 = dt * 32;
#pragma unroll
  for (int p = 0; p < 4; p++) {
    int ss = ty + p * 8;
    ld[ss][tx] = qkv[(size_t)(s0 + ss) * NDm + 6144 + h * 128 + d0 + tx];
  }
  __syncthreads();
#pragma unroll
  for (int p = 0; p < 4; p++) {
    int dd = ty + p * 8;
    vt[((size_t)h * 128 + d0 + dd) * Sq + s0 + tx] = f2bf(ld[tx][dd]);
  }
}

// ---------------- flash attention v3: LDS-staged, double-buffered ----------
// 4 waves/block, 64 q rows/block (16/wave, full KV per wave -> no combine).
// KV tile = 64 keys: K[64][128] + V^T[128][64] in LDS, XOR-swizzled via
// pre-swizzled global_load_lds source (slot ^= row&7 on 16B units).
// 2-phase: stage(kt+1) issued before compute(kt); one barrier per tile.
__global__ __launch_bounds__(256) void attn_kernel(
    const unsigned short* __restrict__ qh,  // [NH][1152][128]
    const unsigned short* __restrict__ kh,  // [NH][2176][128]
    const unsigned short* __restrict__ vt,  // [NH][128][2176]
    float* __restrict__ out) {              // [1152][3072] f32
  // bijective XCD chunk swizzle: 432 blocks, 54/XCD -> 3 heads per XCD
  int id = blockIdx.x;
  int wg = (id & 7) * 54 + (id >> 3);
  int h = wg / 18, qt = wg % 18;
  int q0 = qt * 64;

  int t = threadIdx.x;
  int w = t >> 6, lane = t & 63;
  int lr = lane & 15, lg = lane >> 4;

  __shared__ __attribute__((aligned(16))) unsigned short kLds[2][64 * 128];
  __shared__ __attribute__((aligned(16))) unsigned short vLds[2][128 * 64];
  __shared__ __attribute__((aligned(16))) unsigned short pl[4][16][72]; // 144B rows

  // ---- Q fragments (16 rows per wave) ----
  const unsigned short* qb = qh + ((size_t)h * BLKR + q0 + w * 16) * 128;
  bf16x8 aq[4];
#pragma unroll
  for (int m = 0; m < 4; m++)
    aq[m] = *(const bf16x8*)(qb + (size_t)lr * 128 + m * 32 + lg * 8);

  // ---- staging source pointers (pre-swizzled per lane) ----
  const unsigned short* kh_h = kh + (size_t)h * Sq * 128;
  const unsigned short* vt_h = vt + (size_t)h * 128 * Sq;
  int l16 = lane >> 4, s16 = lane & 15;
  int l8 = lane >> 3, s8 = lane & 7;
  const unsigned short* srcK[4];
  const unsigned short* srcV[4];
  int kRowB[4], vRowB[4];
#pragma unroll
  for (int c = 0; c < 4; c++) {
    int rK = w * 16 + c * 4 + l16;            // tile row 0..63
    srcK[c] = kh_h + (size_t)rK * 128 + ((s16 ^ (rK & 7)) * 8);
    kRowB[c] = (w * 16 + c * 4) * 128;        // LDS elem offset of call base
    int rV = (w * 4 + c) * 8 + l8;            // d row 0..127
    srcV[c] = vt_h + (size_t)rV * Sq + ((s8 ^ (rV & 7)) * 8);
    vRowB[c] = (w * 4 + c) * 512;
  }

  auto stage = [&](int kt, int buf) {
#pragma unroll
    for (int c = 0; c < 4; c++)
      __builtin_amdgcn_global_load_lds(
          (const __attribute__((address_space(1))) void*)(srcK[c] + (size_t)kt * 8192),
          (__attribute__((address_space(3))) void*)(&kLds[buf][kRowB[c]]), 16, 0, 0);
#pragma unroll
    for (int c = 0; c < 4; c++)
      __builtin_amdgcn_global_load_lds(
          (const __attribute__((address_space(1))) void*)(srcV[c] + (size_t)kt * 64),
          (__attribute__((address_space(3))) void*)(&vLds[buf][vRowB[c]]), 16, 0, 0);
  };

  f32x4 acc[8];
#pragma unroll
  for (int o = 0; o < 8; o++) acc[o] = (f32x4){0.f, 0.f, 0.f, 0.f};
  float lsum[4] = {0.f, 0.f, 0.f, 0.f};
  float M = -3.0e38f;
  const float sc = 0.08838834764831845f;   // 1/sqrt(128)
  const float L2E = 1.4426950408889634f;

  int lr7 = lr & 7;

  auto compute = [&](int buf) {
    const unsigned short* kbuf = kLds[buf];
    const unsigned short* vbuf = vLds[buf];
    f32x4 s2[4];
#pragma unroll
    for (int tt = 0; tt < 4; tt++) s2[tt] = (f32x4){0.f, 0.f, 0.f, 0.f};
#pragma unroll
    for (int tt = 0; tt < 4; tt++)
#pragma unroll
      for (int m = 0; m < 4; m++) {
        bf16x8 kf = *(const bf16x8*)&kbuf[(tt * 16 + lr) * 128 + ((m * 4 + lg) ^ lr7) * 8];
        s2[tt] = __builtin_amdgcn_mfma_f32_16x16x32_bf16(aq[m], kf, s2[tt], 0, 0, 0);
      }
    // wave-uniform tile max
    float tm = -3.0e38f;
#pragma unroll
    for (int tt = 0; tt < 4; tt++)
#pragma unroll
      for (int i = 0; i < 4; i++) tm = fmaxf(tm, s2[tt][i]);
#pragma unroll
    for (int d = 1; d < 64; d <<= 1) tm = fmaxf(tm, __shfl_xor(tm, d, 64));
    tm *= sc;
    if (tm > M + 8.0f) {           // deferred rescale, wave-uniform
      float r = exp2f((M - tm) * L2E);
      M = tm;
#pragma unroll
      for (int o = 0; o < 8; o++)
#pragma unroll
        for (int i = 0; i < 4; i++) acc[o][i] *= r;
#pragma unroll
      for (int i = 0; i < 4; i++) lsum[i] *= r;
    }
    float ea = sc * L2E, eb = -M * L2E;
#pragma unroll
    for (int tt = 0; tt < 4; tt++)
#pragma unroll
      for (int i = 0; i < 4; i++) {
        float p = exp2f(fmaf(s2[tt][i], ea, eb));
        lsum[i] += p;
        pl[w][lg * 4 + i][tt * 16 + lr] = f2bf(p);
      }
    bf16x8 ap0 = *(const bf16x8*)&pl[w][lr][lg * 8];
    bf16x8 ap1 = *(const bf16x8*)&pl[w][lr][32 + lg * 8];
#pragma unroll
    for (int o = 0; o < 8; o++) {
      bf16x8 vf0 = *(const bf16x8*)&vbuf[(o * 16 + lr) * 64 + (lg ^ lr7) * 8];
      bf16x8 vf1 = *(const bf16x8*)&vbuf[(o * 16 + lr) * 64 + ((4 + lg) ^ lr7) * 8];
      acc[o] = __builtin_amdgcn_mfma_f32_16x16x32_bf16(ap0, vf0, acc[o], 0, 0, 0);
      acc[o] = __builtin_amdgcn_mfma_f32_16x16x32_bf16(ap1, vf1, acc[o], 0, 0, 0);
    }
  };

  stage(0, 0);
  __syncthreads();
  for (int kt = 0; kt < NT; kt += 2) {
    stage(kt + 1, 1);
    compute(0);
    __syncthreads();
    if (kt + 2 < NT) stage(kt + 2, 0);
    compute(1);
    __syncthreads();
  }

  // ---- epilogue: per-row l reduce over the 16 lr lanes, write out ----
#pragma unroll
  for (int i = 0; i < 4; i++) {
#pragma unroll
    for (int d = 1; d < 16; d <<= 1) lsum[i] += __shfl_xor(lsum[i], d, 64);
    lsum[i] = 1.f / lsum[i];
  }
#pragma unroll
  for (int o = 0; o < 8; o++) {
    int col = h * 128 + o * 16 + lr;
#pragma unroll
    for (int i = 0; i < 4; i++) {
      int r = q0 + w * 16 + lg * 4 + i;
      out[(size_t)r * 3072 + col] = acc[o][i] * lsum[i];
    }
  }
}

extern "C" void kernel_launch(void* const* d_in, const int* in_sizes, int n_in,
                              void* d_out, int out_size, void* d_ws, size_t ws_size,
                              hipStream_t stream) {
  const float* hs  = (const float*)d_in[0];
  const float* Wq  = (const float*)d_in[1];
  const float* bq  = (const float*)d_in[2];
  const float* Wk  = (const float*)d_in[3];
  const float* bk  = (const float*)d_in[4];
  const float* Wv  = (const float*)d_in[5];
  const float* bv  = (const float*)d_in[6];
  const float* k_down = (const float*)d_in[9];
  const float* k_up   = (const float*)d_in[10];
  const float* v_down = (const float*)d_in[11];
  const float* v_up   = (const float*)d_in[12];
  const float* nqw = (const float*)d_in[13];
  const float* nkw = (const float*)d_in[14];
  const float* rc  = (const float*)d_in[15];
  const float* rsn = (const float*)d_in[16];
  float* out = (float*)d_out;

  char* ws = (char*)d_ws;
  unsigned short* hsb = (unsigned short*)(ws + 0);          // 13,369,344 B
  unsigned short* wb  = (unsigned short*)(ws + 13369344);   // 56,623,104 B
  float*          qkv = (float*)(ws + 69992448);            // 80,216,064 B
  unsigned short* qh  = (unsigned short*)(ws + 150208512);  //  7,077,888 B
  unsigned short* kh  = (unsigned short*)(ws + 157286400);  // 13,369,344 B
  unsigned short* vtb = (unsigned short*)(ws + 170655744);  // 13,369,344 B

  const int n8_hs = Sq * Dm / 8;
  const int n8_w  = Dm * Dm / 8;
  cvt_kernel<<<dim3((n8_hs + 255) / 256), 256, 0, stream>>>(hs, hsb, n8_hs);
  cvt_kernel<<<dim3((n8_w + 255) / 256), 256, 0, stream>>>(Wq, wb, n8_w);
  cvt_kernel<<<dim3((n8_w + 255) / 256), 256, 0, stream>>>(Wk, wb + (size_t)Dm * Dm, n8_w);
  cvt_kernel<<<dim3((n8_w + 255) / 256), 256, 0, stream>>>(Wv, wb + (size_t)2 * Dm * Dm, n8_w);

  gemm_kernel<<<dim3(NDm / 128, Sq / 128), 256, 0, stream>>>(hsb, wb, bq, bk, bv, qkv);
  lora_kernel<<<dim3(Sq - BLKR), 256, 0, stream>>>(hs, k_down, k_up, v_down, v_up, qkv);
  prep_kernel<<<dim3(Sq, NH), 64, 0, stream>>>(qkv, nqw, nkw, rc, rsn, qh, kh);
  vt_kernel<<<dim3(Sq / 32, HDm / 32, NH), 256, 0, stream>>>(qkv, vtb);
  attn_kernel<<<dim3(18 * NH), 256, 0, stream>>>(qh, kh, vtb, out);
}